// Round 14
// baseline (371.060 us; speedup 1.0000x reference)
//
#include <hip/hip_runtime.h>
#include <math.h>

#define KK 64
#define DD 256
#define GX 256        // blocks per feature; grid = 512 = 2 blocks/CU
#define CH 16         // rows per MFMA chunk (K of 32x32x16)
#define MAXCHUNK 512  // max rows per block (N <= GX*MAXCHUNK)
#define INV_TAU 2.0f
#define EPSL 1e-8f

typedef unsigned int u32;
typedef __attribute__((ext_vector_type(4))) u32 u32x4;
typedef __attribute__((ext_vector_type(8))) short s16x8;
typedef __attribute__((ext_vector_type(16))) float f32x16;

__device__ __forceinline__ u32 f2bf(float f) {
    u32 u = __builtin_bit_cast(u32, f);
    return (u + 0x7FFFu + ((u >> 16) & 1u)) >> 16;
}

// ws float layout:
// P : [2][GX][K*D]; C : [2][GX][K]; AR : [2][K*D]; lossk : [K]; scratch : [8]

// ---------------- production seg kernel (R13, proven) ----------------

__global__ __launch_bounds__(512, 4) void seg_mfma_kernel(
    const float* __restrict__ fa, const float* __restrict__ fr,
    const int* __restrict__ la, const int* __restrict__ lr,
    float* __restrict__ P, float* __restrict__ C, int N)
{
    __shared__ int lbl[MAXCHUNK];
    __shared__ int cnt[KK];

    const int tid = threadIdx.x;
    const int g = blockIdx.x, f = blockIdx.y;
    const float* __restrict__ feat = f ? fr : fa;
    const int* __restrict__ label = f ? lr : la;

    if (tid < KK) cnt[tid] = 0;

    const int chunkR = (N + GX - 1) / GX;
    const int n0 = g * chunkR;
    int rows = min(N, n0 + chunkR) - n0;
    if (rows < 0) rows = 0;

    __syncthreads();
    for (int i = tid; i < rows; i += 512) lbl[i] = label[n0 + i];
    __syncthreads();
    for (int i = tid; i < rows; i += 512) atomicAdd(&cnt[lbl[i]], 1);

    const int w = tid >> 6, lane = tid & 63;
    const int half = lane >> 5;
    const int nn = lane & 31;
    const int col0 = w * 32;

    f32x16 acc0 = {0.0f}, acc1 = {0.0f};
    const int nfull = rows / CH;
    const u32 voff = (u32)(half * 8 * DD + col0 + nn) * 4u;

    #define LOADA(dst, t)                                                       \
    do {                                                                        \
        const float* p0_ = feat + (size_t)(n0 + (t) * CH) * DD;                 \
        const float* p1_ = p0_ + 4 * DD;                                        \
        asm volatile(                                                           \
            "global_load_dword %0, %8, %9\n\t"                                  \
            "global_load_dword %1, %8, %9 offset:1024\n\t"                      \
            "global_load_dword %2, %8, %9 offset:2048\n\t"                      \
            "global_load_dword %3, %8, %9 offset:3072\n\t"                      \
            "global_load_dword %4, %8, %10\n\t"                                 \
            "global_load_dword %5, %8, %10 offset:1024\n\t"                     \
            "global_load_dword %6, %8, %10 offset:2048\n\t"                     \
            "global_load_dword %7, %8, %10 offset:3072"                         \
            : "=&v"(dst[0]), "=&v"(dst[1]), "=&v"(dst[2]), "=&v"(dst[3]),       \
              "=&v"(dst[4]), "=&v"(dst[5]), "=&v"(dst[6]), "=&v"(dst[7])        \
            : "v"(voff), "s"(p0_), "s"(p1_)                                     \
            : "memory");                                                        \
    } while (0)

    #define STEP(buf, tt)                                                       \
    if ((tt) < nfull) {                                                         \
        const int rb_ = (tt) * CH + half * 8;                                   \
        int lv[8]; u32 a0p[4], a1p[4];                                          \
        _Pragma("unroll")                                                       \
        for (int j_ = 0; j_ < 8; ++j_) lv[j_] = lbl[rb_ + j_];                  \
        _Pragma("unroll")                                                       \
        for (int p_ = 0; p_ < 4; ++p_) {                                        \
            const int j0_ = 2 * p_, j1_ = 2 * p_ + 1;                           \
            a0p[p_] = ((lv[j0_] == nn)      ? 0x3F80u : 0u) |                   \
                      ((lv[j1_] == nn)      ? 0x3F800000u : 0u);                \
            a1p[p_] = ((lv[j0_] == nn + 32) ? 0x3F80u : 0u) |                   \
                      ((lv[j1_] == nn + 32) ? 0x3F800000u : 0u);                \
        }                                                                       \
        const int rem_ = nfull - 1 - (tt);                                      \
        if (rem_ >= 3)      { asm volatile("s_waitcnt vmcnt(24)" ::: "memory"); } \
        else if (rem_ == 2) { asm volatile("s_waitcnt vmcnt(16)" ::: "memory"); } \
        else if (rem_ == 1) { asm volatile("s_waitcnt vmcnt(8)"  ::: "memory"); } \
        else                { asm volatile("s_waitcnt vmcnt(0)"  ::: "memory"); } \
        __builtin_amdgcn_sched_barrier(0);                                      \
        u32 bpk[4];                                                             \
        _Pragma("unroll")                                                       \
        for (int p_ = 0; p_ < 4; ++p_)                                          \
            bpk[p_] = f2bf(buf[2 * p_]) | (f2bf(buf[2 * p_ + 1]) << 16);        \
        const s16x8 A0 = __builtin_bit_cast(s16x8, (u32x4){a0p[0], a0p[1], a0p[2], a0p[3]}); \
        const s16x8 A1 = __builtin_bit_cast(s16x8, (u32x4){a1p[0], a1p[1], a1p[2], a1p[3]}); \
        const s16x8 Bf = __builtin_bit_cast(s16x8, (u32x4){bpk[0], bpk[1], bpk[2], bpk[3]}); \
        acc0 = __builtin_amdgcn_mfma_f32_32x32x16_bf16(A0, Bf, acc0, 0, 0, 0);  \
        acc1 = __builtin_amdgcn_mfma_f32_32x32x16_bf16(A1, Bf, acc1, 0, 0, 0);  \
        if ((tt) + 4 < nfull) LOADA(buf, (tt) + 4);                             \
    }

    float b0[8], b1[8], b2[8], b3[8];
    if (nfull > 0) LOADA(b0, 0);
    if (nfull > 1) LOADA(b1, 1);
    if (nfull > 2) LOADA(b2, 2);
    if (nfull > 3) LOADA(b3, 3);
    for (int t = 0; t < nfull; t += 4) {
        STEP(b0, t)
        STEP(b1, t + 1)
        STEP(b2, t + 2)
        STEP(b3, t + 3)
    }

    if (nfull * CH < rows) {
        const int r0 = nfull * CH + half * 8;
        float tv[8];
        int lv[8];
        #pragma unroll
        for (int j = 0; j < 8; ++j) {
            const int rr = r0 + j;
            lv[j] = (rr < rows) ? lbl[rr] : -1;
            tv[j] = feat[(size_t)(n0 + ((rr < rows) ? rr : 0)) * DD + col0 + nn];
        }
        u32 a0p[4], a1p[4], bpk[4];
        #pragma unroll
        for (int p = 0; p < 4; ++p) {
            const int j0 = 2 * p, j1 = 2 * p + 1;
            a0p[p] = ((lv[j0] == nn)      ? 0x3F80u : 0u) |
                     ((lv[j1] == nn)      ? 0x3F800000u : 0u);
            a1p[p] = ((lv[j0] == nn + 32) ? 0x3F80u : 0u) |
                     ((lv[j1] == nn + 32) ? 0x3F800000u : 0u);
            bpk[p] = f2bf(tv[j0]) | (f2bf(tv[j1]) << 16);
        }
        const s16x8 A0 = __builtin_bit_cast(s16x8, (u32x4){a0p[0], a0p[1], a0p[2], a0p[3]});
        const s16x8 A1 = __builtin_bit_cast(s16x8, (u32x4){a1p[0], a1p[1], a1p[2], a1p[3]});
        const s16x8 Bf = __builtin_bit_cast(s16x8, (u32x4){bpk[0], bpk[1], bpk[2], bpk[3]});
        acc0 = __builtin_amdgcn_mfma_f32_32x32x16_bf16(A0, Bf, acc0, 0, 0, 0);
        acc1 = __builtin_amdgcn_mfma_f32_32x32x16_bf16(A1, Bf, acc1, 0, 0, 0);
    }
    #undef LOADA
    #undef STEP

    float* dstb = P + ((size_t)f * GX + g) * (KK * DD);
    #pragma unroll
    for (int rg = 0; rg < 16; ++rg) {
        const int cls = (rg & 3) + 8 * (rg >> 2) + 4 * half;
        dstb[(size_t)cls * DD + col0 + nn] = acc0[rg];
        dstb[(size_t)(cls + 32) * DD + col0 + nn] = acc1[rg];
    }
    __syncthreads();
    if (tid < KK) C[((size_t)f * GX + g) * KK + tid] = (float)cnt[tid];
}

// ---------------- ablation probes: bisect probe_d4a -> R12 ----------------
// All compiler-scheduled (no asm), depth-4 named buffers, 2 reps so they
// exceed seg's 87us and surface in the top-5 by Kernel_Name.

__device__ __forceinline__ void probe_flush(float s, float* slot) {
    #pragma unroll
    for (int d = 1; d < 64; d <<= 1) s += __shfl_xor(s, d, 64);
    __shared__ float red[8];
    const int tid = threadIdx.x;
    if ((tid & 63) == 0) red[tid >> 6] = s;
    __syncthreads();
    if (tid == 0) {
        float t = 0;
        #pragma unroll
        for (int u = 0; u < 8; ++u) t += red[u];
        atomicAdd(slot, t);
    }
}

#define PROBE_PRELUDE                                                           \
    const int tid = threadIdx.x, g = blockIdx.x, f = blockIdx.y;                \
    const float* feat = f ? fr : fa;                                            \
    const int chunkR = (N + GX - 1) / GX;                                       \
    const int n0 = g * chunkR;                                                  \
    int rows = min(N, n0 + chunkR) - n0;                                        \
    if (rows < 0) rows = 0;                                                     \
    const int w = tid >> 6, lane = tid & 63;                                    \
    const int half = lane >> 5, nn = lane & 31;                                 \
    const int col0 = w * 32;                                                    \
    const int nfull = rows / CH;                                                \
    (void)col0; (void)nn; (void)half;

#define PLOADF(dst, t)                                                          \
    do {                                                                        \
        const float* bp_ = feat + (size_t)(n0 + (t) * CH + half * 8) * DD + col0 + nn; \
        _Pragma("unroll")                                                       \
        for (int j_ = 0; j_ < 8; ++j_) dst[j_] = bp_[j_ * DD];                  \
    } while (0)

// pv0: loads + adds only (probe_d4a anchor)
__global__ __launch_bounds__(512, 4) void pv0_loads(
    const float* __restrict__ fa, const float* __restrict__ fr,
    const int* __restrict__ la, const int* __restrict__ lr,
    float* __restrict__ scratch, int N)
{
    PROBE_PRELUDE
    float s = 0.0f;
    for (int rep = 0; rep < 2; ++rep) {
        float b0[8], b1[8], b2[8], b3[8];
        if (nfull > 0) PLOADF(b0, 0);
        if (nfull > 1) PLOADF(b1, 1);
        if (nfull > 2) PLOADF(b2, 2);
        if (nfull > 3) PLOADF(b3, 3);
        #define PCONS(b) { _Pragma("unroll") for (int j = 0; j < 8; ++j) s += b[j]; }
        for (int t = 0; t < nfull; t += 4) {
            { PCONS(b0) if (t + 4 < nfull) PLOADF(b0, t + 4); }
            if (t + 1 < nfull) { PCONS(b1) if (t + 5 < nfull) PLOADF(b1, t + 5); }
            if (t + 2 < nfull) { PCONS(b2) if (t + 6 < nfull) PLOADF(b2, t + 6); }
            if (t + 3 < nfull) { PCONS(b3) if (t + 7 < nfull) PLOADF(b3, t + 7); }
        }
        #undef PCONS
        asm volatile("" : "+v"(s));
    }
    probe_flush(s, &scratch[0]);
}

// pv1: + label LDS staging/reads + A-pack
__global__ __launch_bounds__(512, 4) void pv1_apack(
    const float* __restrict__ fa, const float* __restrict__ fr,
    const int* __restrict__ la, const int* __restrict__ lr,
    float* __restrict__ scratch, int N)
{
    __shared__ int lbl[MAXCHUNK];
    PROBE_PRELUDE
    const int* label = f ? lr : la;
    for (int i = tid; i < rows; i += 512) lbl[i] = label[n0 + i];
    __syncthreads();
    float s = 0.0f;
    for (int rep = 0; rep < 2; ++rep) {
        float b0[8], b1[8], b2[8], b3[8];
        if (nfull > 0) PLOADF(b0, 0);
        if (nfull > 1) PLOADF(b1, 1);
        if (nfull > 2) PLOADF(b2, 2);
        if (nfull > 3) PLOADF(b3, 3);
        #define PCONS(b, tt) {                                                  \
            const int rb_ = (tt) * CH + half * 8;                               \
            int lv[8]; u32 a0p[4], a1p[4];                                      \
            _Pragma("unroll")                                                   \
            for (int j_ = 0; j_ < 8; ++j_) lv[j_] = lbl[rb_ + j_];              \
            _Pragma("unroll")                                                   \
            for (int p_ = 0; p_ < 4; ++p_) {                                    \
                const int j0_ = 2 * p_, j1_ = 2 * p_ + 1;                       \
                a0p[p_] = ((lv[j0_] == nn)      ? 0x3F80u : 0u) |               \
                          ((lv[j1_] == nn)      ? 0x3F800000u : 0u);            \
                a1p[p_] = ((lv[j0_] == nn + 32) ? 0x3F80u : 0u) |               \
                          ((lv[j1_] == nn + 32) ? 0x3F800000u : 0u);            \
            }                                                                   \
            s += (float)(a0p[0] ^ a1p[1] ^ a0p[2] ^ a1p[3]);                    \
            _Pragma("unroll")                                                   \
            for (int j_ = 0; j_ < 8; ++j_) s += b[j_]; }
        for (int t = 0; t < nfull; t += 4) {
            { PCONS(b0, t) if (t + 4 < nfull) PLOADF(b0, t + 4); }
            if (t + 1 < nfull) { PCONS(b1, t + 1) if (t + 5 < nfull) PLOADF(b1, t + 5); }
            if (t + 2 < nfull) { PCONS(b2, t + 2) if (t + 6 < nfull) PLOADF(b2, t + 6); }
            if (t + 3 < nfull) { PCONS(b3, t + 3) if (t + 7 < nfull) PLOADF(b3, t + 7); }
        }
        #undef PCONS
        asm volatile("" : "+v"(s));
    }
    probe_flush(s, &scratch[1]);
}

// pv2: + f2bf B-pack (replaces raw adds)
__global__ __launch_bounds__(512, 4) void pv2_bpack(
    const float* __restrict__ fa, const float* __restrict__ fr,
    const int* __restrict__ la, const int* __restrict__ lr,
    float* __restrict__ scratch, int N)
{
    __shared__ int lbl[MAXCHUNK];
    PROBE_PRELUDE
    const int* label = f ? lr : la;
    for (int i = tid; i < rows; i += 512) lbl[i] = label[n0 + i];
    __syncthreads();
    float s = 0.0f;
    u32 us = 0;
    for (int rep = 0; rep < 2; ++rep) {
        float b0[8], b1[8], b2[8], b3[8];
        if (nfull > 0) PLOADF(b0, 0);
        if (nfull > 1) PLOADF(b1, 1);
        if (nfull > 2) PLOADF(b2, 2);
        if (nfull > 3) PLOADF(b3, 3);
        #define PCONS(b, tt) {                                                  \
            const int rb_ = (tt) * CH + half * 8;                               \
            int lv[8]; u32 a0p[4], a1p[4], bpk[4];                              \
            _Pragma("unroll")                                                   \
            for (int j_ = 0; j_ < 8; ++j_) lv[j_] = lbl[rb_ + j_];              \
            _Pragma("unroll")                                                   \
            for (int p_ = 0; p_ < 4; ++p_) {                                    \
                const int j0_ = 2 * p_, j1_ = 2 * p_ + 1;                       \
                a0p[p_] = ((lv[j0_] == nn)      ? 0x3F80u : 0u) |               \
                          ((lv[j1_] == nn)      ? 0x3F800000u : 0u);            \
                a1p[p_] = ((lv[j0_] == nn + 32) ? 0x3F80u : 0u) |               \
                          ((lv[j1_] == nn + 32) ? 0x3F800000u : 0u);            \
                bpk[p_] = f2bf(b[2 * p_]) | (f2bf(b[2 * p_ + 1]) << 16);        \
            }                                                                   \
            us ^= a0p[0] ^ a1p[1] ^ bpk[0] ^ bpk[1] ^ bpk[2] ^ bpk[3]; }
        for (int t = 0; t < nfull; t += 4) {
            { PCONS(b0, t) if (t + 4 < nfull) PLOADF(b0, t + 4); }
            if (t + 1 < nfull) { PCONS(b1, t + 1) if (t + 5 < nfull) PLOADF(b1, t + 5); }
            if (t + 2 < nfull) { PCONS(b2, t + 2) if (t + 6 < nfull) PLOADF(b2, t + 6); }
            if (t + 3 < nfull) { PCONS(b3, t + 3) if (t + 7 < nfull) PLOADF(b3, t + 7); }
        }
        #undef PCONS
        asm volatile("" : "+v"(us));
    }
    probe_flush(s + (float)us, &scratch[2]);
}

// pv3: + MFMA (full R12 hot loop)
__global__ __launch_bounds__(512, 4) void pv3_mfma(
    const float* __restrict__ fa, const float* __restrict__ fr,
    const int* __restrict__ la, const int* __restrict__ lr,
    float* __restrict__ scratch, int N)
{
    __shared__ int lbl[MAXCHUNK];
    PROBE_PRELUDE
    const int* label = f ? lr : la;
    for (int i = tid; i < rows; i += 512) lbl[i] = label[n0 + i];
    __syncthreads();
    f32x16 acc0 = {0.0f}, acc1 = {0.0f};
    for (int rep = 0; rep < 2; ++rep) {
        float b0[8], b1[8], b2[8], b3[8];
        if (nfull > 0) PLOADF(b0, 0);
        if (nfull > 1) PLOADF(b1, 1);
        if (nfull > 2) PLOADF(b2, 2);
        if (nfull > 3) PLOADF(b3, 3);
        #define PCONS(b, tt) {                                                  \
            const int rb_ = (tt) * CH + half * 8;                               \
            int lv[8]; u32 a0p[4], a1p[4], bpk[4];                              \
            _Pragma("unroll")                                                   \
            for (int j_ = 0; j_ < 8; ++j_) lv[j_] = lbl[rb_ + j_];              \
            _Pragma("unroll")                                                   \
            for (int p_ = 0; p_ < 4; ++p_) {                                    \
                const int j0_ = 2 * p_, j1_ = 2 * p_ + 1;                       \
                a0p[p_] = ((lv[j0_] == nn)      ? 0x3F80u : 0u) |               \
                          ((lv[j1_] == nn)      ? 0x3F800000u : 0u);            \
                a1p[p_] = ((lv[j0_] == nn + 32) ? 0x3F80u : 0u) |               \
                          ((lv[j1_] == nn + 32) ? 0x3F800000u : 0u);            \
                bpk[p_] = f2bf(b[2 * p_]) | (f2bf(b[2 * p_ + 1]) << 16);        \
            }                                                                   \
            const s16x8 A0 = __builtin_bit_cast(s16x8, (u32x4){a0p[0], a0p[1], a0p[2], a0p[3]}); \
            const s16x8 A1 = __builtin_bit_cast(s16x8, (u32x4){a1p[0], a1p[1], a1p[2], a1p[3]}); \
            const s16x8 Bf = __builtin_bit_cast(s16x8, (u32x4){bpk[0], bpk[1], bpk[2], bpk[3]}); \
            acc0 = __builtin_amdgcn_mfma_f32_32x32x16_bf16(A0, Bf, acc0, 0, 0, 0); \
            acc1 = __builtin_amdgcn_mfma_f32_32x32x16_bf16(A1, Bf, acc1, 0, 0, 0); }
        for (int t = 0; t < nfull; t += 4) {
            { PCONS(b0, t) if (t + 4 < nfull) PLOADF(b0, t + 4); }
            if (t + 1 < nfull) { PCONS(b1, t + 1) if (t + 5 < nfull) PLOADF(b1, t + 5); }
            if (t + 2 < nfull) { PCONS(b2, t + 2) if (t + 6 < nfull) PLOADF(b2, t + 6); }
            if (t + 3 < nfull) { PCONS(b3, t + 3) if (t + 7 < nfull) PLOADF(b3, t + 7); }
        }
        #undef PCONS
    }
    float s = 0.0f;
    #pragma unroll
    for (int rg = 0; rg < 16; ++rg) s += acc0[rg] + acc1[rg];
    probe_flush(s, &scratch[3]);
}

// ---------------- downstream (unchanged, proven) ----------------

__global__ __launch_bounds__(256) void proto_norm_kernel(
    const float* __restrict__ P, const float* __restrict__ C,
    float* __restrict__ AR, int G)
{
    const int k = blockIdx.x, f = blockIdx.y, tid = threadIdx.x;
    const float* base = P + (size_t)f * G * (KK * DD) + (size_t)k * DD + tid;

    float s = 0.0f;
    int g = 0;
    for (; g + 8 <= G; g += 8) {
        float v[8];
        #pragma unroll
        for (int u = 0; u < 8; ++u) v[u] = base[(size_t)(g + u) * (KK * DD)];
        #pragma unroll
        for (int u = 0; u < 8; ++u) s += v[u];
    }
    for (; g < G; ++g) s += base[(size_t)g * (KK * DD)];

    float c = 0.0f;
    const float* cb = C + (size_t)f * G * KK + k;
    for (int g2 = 0; g2 < G; ++g2) c += cb[(size_t)g2 * KK];

    const float m = s / c;
    float sq = m * m;
    #pragma unroll
    for (int i = 1; i < 64; i <<= 1) sq += __shfl_xor(sq, i, 64);
    __shared__ float red[4];
    const int wid = tid >> 6, lane = tid & 63;
    if (lane == 0) red[wid] = sq;
    __syncthreads();
    const float nrm = red[0] + red[1] + red[2] + red[3];
    AR[(size_t)f * KK * DD + (size_t)k * DD + tid] = m / fmaxf(sqrtf(nrm), 1e-12f);
}

__global__ __launch_bounds__(256) void loss_kernel(const float* __restrict__ AR,
                                                   float* __restrict__ lossk)
{
    const float* A = AR;
    const float* R = AR + KK * DD;
    const int k = blockIdx.x, tid = threadIdx.x;

    const float a = A[k * DD + tid];
    const float r = R[k * DD + tid];
    const float lfp = a * r * INV_TAU;
    const float fp = expf(lfp);
    float ssa = 0.0f, ssr = 0.0f;
    #pragma unroll 8
    for (int j = 0; j < KK; ++j) {
        ssa += expf(a * A[j * DD + tid] * INV_TAU);
        ssr += expf(a * R[j * DD + tid] * INV_TAU);
    }
    const float Fn = (ssa - expf(a * a * INV_TAU)) + (ssr - fp) + 2.0f * (KK - 1) * fp;
    float l = logf(Fn + EPSL) - lfp;

    #pragma unroll
    for (int i = 1; i < 64; i <<= 1) l += __shfl_xor(l, i, 64);
    __shared__ float red[4];
    const int wid = tid >> 6, lane = tid & 63;
    if (lane == 0) red[wid] = l;
    __syncthreads();
    if (tid == 0) lossk[k] = (red[0] + red[1] + red[2] + red[3]) * (1.0f / DD);
}

__global__ void final_kernel(const float* __restrict__ lossk, float* __restrict__ out)
{
    float v = lossk[threadIdx.x];
    #pragma unroll
    for (int i = 1; i < 64; i <<= 1) v += __shfl_xor(v, i, 64);
    if (threadIdx.x == 0) out[0] = v;
}

extern "C" void kernel_launch(void* const* d_in, const int* in_sizes, int n_in,
                              void* d_out, int out_size, void* d_ws, size_t ws_size,
                              hipStream_t stream)
{
    const float* fa = (const float*)d_in[0];
    const float* fr = (const float*)d_in[1];
    const int* la = (const int*)d_in[2];
    const int* lr = (const int*)d_in[3];
    float* ws = (float*)d_ws;
    float* out = (float*)d_out;
    const int N = in_sizes[2];

    float* P = ws;                                  // [2][GX][K*D]
    float* C = P + 2L * GX * KK * DD;               // [2][GX][K]
    float* AR = C + 2L * GX * KK;                   // [2][K*D]
    float* lossk = AR + 2L * KK * DD;               // [K]
    float* scratch = lossk + KK;                    // [8] probe slots (never read)

    seg_mfma_kernel<<<dim3(GX, 2), 512, 0, stream>>>(fa, fr, la, lr, P, C, N);
    proto_norm_kernel<<<dim3(KK, 2), 256, 0, stream>>>(P, C, AR, GX);
    loss_kernel<<<KK, 256, 0, stream>>>(AR, lossk);
    final_kernel<<<1, 64, 0, stream>>>(lossk, out);

    // ablation chain probe_d4a -> R12 (2 reps each, after output is produced)
    pv0_loads<<<dim3(GX, 2), 512, 0, stream>>>(fa, fr, la, lr, scratch, N);
    pv1_apack<<<dim3(GX, 2), 512, 0, stream>>>(fa, fr, la, lr, scratch, N);
    pv2_bpack<<<dim3(GX, 2), 512, 0, stream>>>(fa, fr, la, lr, scratch, N);
    pv3_mfma<<<dim3(GX, 2), 512, 0, stream>>>(fa, fr, la, lr, scratch, N);
}